// Round 7
// baseline (6495.401 us; speedup 1.0000x reference)
//
#include <hip/hip_runtime.h>
#include <hip/hip_bf16.h>

typedef __bf16 bf16x8 __attribute__((ext_vector_type(8)));
typedef float  f32x4  __attribute__((ext_vector_type(4)));

#define LR_C 0.001f
#define VMCNT(n) asm volatile("s_waitcnt vmcnt(" #n ")" ::: "memory")
#define CFENCE() asm volatile("" ::: "memory")

__device__ __forceinline__ float sigf(float x){ return 1.0f/(1.0f + __expf(-x)); }
__device__ __forceinline__ ushort f2bu(float x){ __hip_bfloat16 h = __float2bfloat16(x); return *(ushort*)&h; }
__device__ __forceinline__ float bu2f(ushort u){ __hip_bfloat16 h = *(__hip_bfloat16*)&u; return __bfloat162float(h); }

__device__ __forceinline__ void gload_lds16(const void* g, void* l){
  __builtin_amdgcn_global_load_lds(
      (const __attribute__((address_space(1))) void*)g,
      (__attribute__((address_space(3))) void*)l, 16, 0, 0);
}

// ---------------- prep kernels ----------------

__global__ void k_cvt_bf16(__hip_bfloat16* dst, const float* src, int n){
  int i = blockIdx.x*256 + threadIdx.x;
  if (i < n) dst[i] = __float2bfloat16(src[i]);
}

__global__ void k_cvt_pad(__hip_bfloat16* dst, const float* src, int rows, int cs, int cd){
  int i = blockIdx.x*256 + threadIdx.x;
  if (i >= rows*cd) return;
  int r = i / cd, c = i % cd;
  float v = (c < cs) ? src[r*cs + c] : 0.0f;
  dst[i] = __float2bfloat16(v);
}

// dst[n][j] (n<sc, stride dstride, j>=sr zero) = src[j][n]
__global__ void k_transpose(__hip_bfloat16* dst, const float* src, int sr, int sc, int dstride){
  int i = blockIdx.x*256 + threadIdx.x;
  if (i >= sc*dstride) return;
  int n = i / dstride, j = i % dstride;
  float v = (j < sr) ? src[j*sc + n] : 0.0f;
  dst[i] = __float2bfloat16(v);
}

__global__ void k_init_state(float* sf, __hip_bfloat16* A, const float* s, int n){
  int i = blockIdx.x*256 + threadIdx.x;
  if (i >= n) return;
  float v = s[i];
  sf[i] = v;
  A[i] = __float2bfloat16(sigf(v));
}

// s3: 8192x10 -> s3f (stride 10), A3 (stride 32, cols 10..31 = 0)
__global__ void k_init_s3(float* s3f, __hip_bfloat16* A3, const float* s3){
  int i = blockIdx.x*256 + threadIdx.x;
  if (i >= 8192*32) return;
  int b = i >> 5, c = i & 31;
  if (c < 10){
    float v = s3[b*10 + c];
    s3f[b*10 + c] = v;
    A3[i] = __float2bfloat16(sigf(v));
  } else {
    A3[i] = __float2bfloat16(0.0f);
  }
}

__global__ void k_zero_bf16(__hip_bfloat16* p, int n){
  int i = blockIdx.x*256 + threadIdx.x;
  if (i < n) p[i] = __float2bfloat16(0.0f);
}

__global__ void k_copy_f32(float* dst, const float* src, int n){
  int i = blockIdx.x*256 + threadIdx.x;
  if (i < n) dst[i] = src[i];
}

// ---------------- 64x128 / BK=32 / 4-wave NT GEMM, 2-deep pipelined ----
// C = A(8192xK) * B(NxK)^T tile at (brow,bcol); Nclamp clamps B staging rows.
// LDS: As [2][64][32], Bs [2][128][32] ushort (24 KB total).
// Wave w owns cols [w*32, w*32+32): frags acc[m 0..3][n 0..1].
// Source col and ds_read col XOR-swizzled by (row&3)<<3 (both-sides).

__device__ __forceinline__ void gemm64(
    const ushort* __restrict__ A, const ushort* __restrict__ B,
    int lda, int ldb, int K, int Nclamp,
    int brow, int bcol, int t, ushort* As, ushort* Bs, f32x4 (&acc)[4][2])
{
  const int w   = t >> 6;
  const int l   = t & 63;
  const int fr  = l & 15;
  const int ks  = (l >> 4) * 8;
  const int rks = ks ^ ((fr & 3) << 3);

#pragma unroll
  for (int m=0;m<4;m++){ acc[m][0]=(f32x4){0.f,0.f,0.f,0.f}; acc[m][1]=(f32x4){0.f,0.f,0.f,0.f}; }

  const int srow = t >> 2;                               // 0..63
  const int scol = ((t & 3) * 8) ^ ((srow & 3) << 3);    // swizzled source col
  const ushort* gA = A + (size_t)(brow + srow) * lda + scol;
  int rb  = bcol + srow;      if (rb  > Nclamp-1) rb  = Nclamp-1;
  int rb2 = bcol + 64 + srow; if (rb2 > Nclamp-1) rb2 = Nclamp-1;
  const ushort* gB  = B + (size_t)rb  * ldb + scol;      // (64+srow)&3 == srow&3
  const ushort* gB2 = B + (size_t)rb2 * ldb + scol;

  auto STAGE = [&](int buf, int k0){
    gload_lds16(gA  + k0, As + buf*2048 + w*512);
    gload_lds16(gB  + k0, Bs + buf*4096 + w*512);
    gload_lds16(gB2 + k0, Bs + buf*4096 + 2048 + w*512);
  };

  const int nt = K >> 5;
  STAGE(0, 0);
  if (nt > 1) STAGE(1, 32);

  int cur = 0;
  for (int tk = 0; tk < nt; ++tk){
    if (tk + 1 < nt) { VMCNT(3); } else { VMCNT(0); }
    __builtin_amdgcn_s_barrier();
    CFENCE();
    const ushort* Ab = As + cur*2048;
    const ushort* Bb = Bs + cur*4096;
    bf16x8 af[4], bfv[2];
#pragma unroll
    for (int m=0;m<4;m++) af[m]  = *(const bf16x8*)&Ab[(m*16 + fr)*32 + rks];
#pragma unroll
    for (int n=0;n<2;n++) bfv[n] = *(const bf16x8*)&Bb[(w*32 + n*16 + fr)*32 + rks];
#pragma unroll
    for (int m=0;m<4;m++)
#pragma unroll
      for (int n=0;n<2;n++)
        acc[m][n] = __builtin_amdgcn_mfma_f32_16x16x32_bf16(af[m], bfv[n], acc[m][n], 0, 0, 0);
    CFENCE();
    __builtin_amdgcn_s_barrier();
    CFENCE();
    if (tk + 2 < nt) STAGE(cur, (tk+2)*32);
    cur ^= 1;
  }
}

// XCD-aware block map: by%8 == lid%8 so all bx-tiles of a row-band share an XCD
__device__ __forceinline__ void blockmap(int lid, int nbx, int& brow, int& bcol){
  int by = (lid & 7) + 8 * ((lid >> 3) / nbx);
  int bx = (lid >> 3) % nbx;
  brow = by * 64; bcol = bx * 128;
}

// ---------------- fused dispatch kernels ----------------
// D1 = { U2 [0,512) | U3 [512,640) | P1 [640,1536) }
// D2 = { P3 [0,512) | P2U1 [512,1536) }

__global__ __launch_bounds__(256, 6)
void fusedD1(int base,
             const ushort* __restrict__ A1, const ushort* __restrict__ W1b,
             const ushort* __restrict__ inb, ushort* __restrict__ e0, float* p0out,
             const ushort* __restrict__ e1b, const ushort* __restrict__ W2T,
             float* __restrict__ s2f, const ushort* __restrict__ e2b,
             ushort* __restrict__ A2,
             const ushort* __restrict__ W3T, float* __restrict__ s3f,
             ushort* __restrict__ A3)
{
  __shared__ __align__(16) ushort As[2*2048];
  __shared__ __align__(16) ushort Bs[2*4096];
  const int bid = blockIdx.x + base;
  const int t = threadIdx.x;
  const int w = t >> 6, l = t & 63;
  const int fr = l & 15, r4 = (l >> 4) * 4;
  f32x4 acc[4][2];

  if (bid < 512){                      // U2: s2 += LR*(-e2 + sig'(s2)*(e1@W2))
    int brow, bcol; blockmap(bid, 4, brow, bcol);
    gemm64(e1b, W2T, 1024, 1024, 1024, 512, brow, bcol, t, As, Bs, acc);
#pragma unroll
    for (int m=0;m<4;m++)
#pragma unroll
      for (int n=0;n<2;n++){
        int col = bcol + w*32 + n*16 + fr;
#pragma unroll
        for (int j=0;j<4;j++){
          int row = brow + m*16 + r4 + j;
          size_t ix = (size_t)row*512 + col;
          float s = s2f[ix];
          float a = sigf(s);
          float e2 = bu2f(e2b[ix]);
          float sn = s + LR_C*(-e2 + a*(1.0f-a)*acc[m][n][j]);
          s2f[ix] = sn;
          A2[ix] = f2bu(sigf(sn));
        }
      }
  } else if (bid < 640){               // U3: s3 += LR*sig'(s3)*(e2@W3)
    int brow = (bid - 512) * 64;
    gemm64(e2b, W3T, 512, 512, 512, 16, brow, 0, t, As, Bs, acc);
#pragma unroll
    for (int m=0;m<4;m++)
#pragma unroll
      for (int n=0;n<2;n++){
        int col = w*32 + n*16 + fr;
        if (col >= 10) continue;
#pragma unroll
        for (int j=0;j<4;j++){
          int row = brow + m*16 + r4 + j;
          float s = s3f[(size_t)row*10 + col];
          float a = sigf(s);
          float sn = s + LR_C*(a*(1.0f-a)*acc[m][n][j]);
          s3f[(size_t)row*10 + col] = sn;
          A3[(size_t)row*32 + col] = f2bu(sigf(sn));
        }
      }
  } else {                             // P1: e0 = inb - A1@W1b^T
    int brow, bcol; blockmap(bid - 640, 7, brow, bcol);
    gemm64(A1, W1b, 1024, 1024, 1024, 784, brow, bcol, t, As, Bs, acc);
#pragma unroll
    for (int m=0;m<4;m++)
#pragma unroll
      for (int n=0;n<2;n++){
        int col = bcol + w*32 + n*16 + fr;
        if (col >= 784) continue;
#pragma unroll
        for (int j=0;j<4;j++){
          int row = brow + m*16 + r4 + j;
          float p = acc[m][n][j];
          float e = bu2f(inb[(size_t)row*784 + col]) - p;
          e0[(size_t)row*800 + col] = f2bu(e);
          if (p0out) p0out[(size_t)row*784 + col] = p;
        }
      }
  }
}

__global__ __launch_bounds__(256, 4)
void fusedD2(const ushort* __restrict__ A2, const ushort* __restrict__ W2b,
             const ushort* __restrict__ e0, const ushort* __restrict__ W1T,
             float* __restrict__ s1f, ushort* __restrict__ A1,
             ushort* __restrict__ e1b,
             const ushort* __restrict__ A3, const ushort* __restrict__ W3b,
             const float* __restrict__ s2f, ushort* __restrict__ e2b)
{
  __shared__ __align__(16) ushort As[2*2048];
  __shared__ __align__(16) ushort Bs[2*4096];
  const int bid = blockIdx.x;
  const int t = threadIdx.x;
  const int w = t >> 6, l = t & 63;
  const int fr = l & 15, r4 = (l >> 4) * 4;

  if (bid < 512){                      // P3: e2 = s2 - A3@W3b^T
    int brow, bcol; blockmap(bid, 4, brow, bcol);
    f32x4 acc[4][2];
    gemm64(A3, W3b, 32, 32, 32, 512, brow, bcol, t, As, Bs, acc);
#pragma unroll
    for (int m=0;m<4;m++)
#pragma unroll
      for (int n=0;n<2;n++){
        int col = bcol + w*32 + n*16 + fr;
#pragma unroll
        for (int j=0;j<4;j++){
          int row = brow + m*16 + r4 + j;
          size_t ix = (size_t)row*512 + col;
          float e2 = s2f[ix] - acc[m][n][j];
          e2b[ix] = f2bu(e2);
        }
      }
  } else {                             // P2U1 merged (dual accumulator)
    int brow, bcol; blockmap(bid - 512, 8, brow, bcol);
    f32x4 aP[4][2], aU[4][2];
    gemm64(A2, W2b, 512, 512, 512, 1024, brow, bcol, t, As, Bs, aP);   // p1
    gemm64(e0, W1T, 800, 800, 800, 1024, brow, bcol, t, As, Bs, aU);   // e0@W1
#pragma unroll
    for (int m=0;m<4;m++)
#pragma unroll
      for (int n=0;n<2;n++){
        int col = bcol + w*32 + n*16 + fr;
#pragma unroll
        for (int j=0;j<4;j++){
          int row = brow + m*16 + r4 + j;
          size_t ix = (size_t)row*1024 + col;
          float s  = s1f[ix];
          float e1 = s - aP[m][n][j];
          float a  = sigf(s);
          float sn = s + LR_C*(-e1 + a*(1.0f-a)*aU[m][n][j]);
          s1f[ix] = sn;
          A1[ix]  = f2bu(sigf(sn));
          e1b[ix] = f2bu(e1);
        }
      }
  }
}

// ---------------- host orchestration ----------------

extern "C" void kernel_launch(void* const* d_in, const int* in_sizes, int n_in,
                              void* d_out, int out_size, void* d_ws, size_t ws_size,
                              hipStream_t stream) {
  const float* input = (const float*)d_in[0];
  const float* s1    = (const float*)d_in[1];
  const float* s2    = (const float*)d_in[2];
  const float* s3    = (const float*)d_in[3];
  const float* W1    = (const float*)d_in[4];
  const float* W2    = (const float*)d_in[5];
  const float* W3    = (const float*)d_in[6];
  float* out = (float*)d_out;

  char* ws = (char*)d_ws;
  size_t off = 0;
  auto take = [&](size_t bytes)->char*{
    char* p = ws + off;
    off = (off + bytes + 255) & ~(size_t)255;
    return p;
  };

  float* s1f = (float*)take(8192ull*1024*4);
  float* s2f = (float*)take(8192ull*512*4);
  float* s3f = (float*)take(8192ull*10*4);
  __hip_bfloat16* A1  = (__hip_bfloat16*)take(8192ull*1024*2);
  __hip_bfloat16* A2  = (__hip_bfloat16*)take(8192ull*512*2);
  __hip_bfloat16* A3  = (__hip_bfloat16*)take(8192ull*32*2);
  __hip_bfloat16* e0  = (__hip_bfloat16*)take(8192ull*800*2);
  __hip_bfloat16* e1b = (__hip_bfloat16*)take(8192ull*1024*2);
  __hip_bfloat16* e2b = (__hip_bfloat16*)take(8192ull*512*2);
  __hip_bfloat16* inb = (__hip_bfloat16*)take(8192ull*784*2);
  __hip_bfloat16* W1b = (__hip_bfloat16*)take(784ull*1024*2);
  __hip_bfloat16* W2b = (__hip_bfloat16*)take(1024ull*512*2);
  __hip_bfloat16* W3b = (__hip_bfloat16*)take(512ull*32*2);
  __hip_bfloat16* W1T = (__hip_bfloat16*)take(1024ull*800*2);
  __hip_bfloat16* W2T = (__hip_bfloat16*)take(512ull*1024*2);
  __hip_bfloat16* W3T = (__hip_bfloat16*)take(16ull*512*2);

  auto cdiv = [](int a, int b){ return (a + b - 1) / b; };

  // --- prep (runs every call; d_ws has no persistent state) ---
  k_cvt_bf16 <<<cdiv(8192*784,256),256,0,stream>>>(inb, input, 8192*784);
  k_cvt_bf16 <<<cdiv(784*1024,256),256,0,stream>>>(W1b, W1, 784*1024);
  k_cvt_bf16 <<<cdiv(1024*512,256),256,0,stream>>>(W2b, W2, 1024*512);
  k_cvt_pad  <<<cdiv(512*32,256),256,0,stream>>>(W3b, W3, 512, 10, 32);
  k_transpose<<<cdiv(1024*800,256),256,0,stream>>>(W1T, W1, 784, 1024, 800);
  k_transpose<<<cdiv(512*1024,256),256,0,stream>>>(W2T, W2, 1024, 512, 1024);
  k_zero_bf16<<<cdiv(16*512,256),256,0,stream>>>(W3T, 16*512);
  k_transpose<<<cdiv(10*512,256),256,0,stream>>>(W3T, W3, 512, 10, 512);
  k_init_state<<<cdiv(8192*1024,256),256,0,stream>>>(s1f, A1, s1, 8192*1024);
  k_init_state<<<cdiv(8192*512,256),256,0,stream>>>(s2f, A2, s2, 8192*512);
  k_init_s3  <<<cdiv(8192*32,256),256,0,stream>>>(s3f, A3, s3);
  k_zero_bf16<<<cdiv(8192*800,256),256,0,stream>>>(e0, 8192*800);   // K-pad cols 784..799

  // --- 60 cycles, 2 dispatches each ---
  for (int c = 0; c < 60; ++c){
    float* p0_dst = (c == 59) ? (out + 8192*10) : nullptr;
    if (c == 0){
      // P1 only (segment [640,1536))
      fusedD1<<<896, 256, 0, stream>>>(640, (const ushort*)A1, (const ushort*)W1b,
          (const ushort*)inb, (ushort*)e0, p0_dst,
          (const ushort*)e1b, (const ushort*)W2T, s2f, (const ushort*)e2b,
          (ushort*)A2, (const ushort*)W3T, s3f, (ushort*)A3);
    } else {
      fusedD1<<<1536, 256, 0, stream>>>(0, (const ushort*)A1, (const ushort*)W1b,
          (const ushort*)inb, (ushort*)e0, p0_dst,
          (const ushort*)e1b, (const ushort*)W2T, s2f, (const ushort*)e2b,
          (ushort*)A2, (const ushort*)W3T, s3f, (ushort*)A3);
    }
    fusedD2<<<1536, 256, 0, stream>>>((const ushort*)A2, (const ushort*)W2b,
        (const ushort*)e0, (const ushort*)W1T, s1f, (ushort*)A1, (ushort*)e1b,
        (const ushort*)A3, (const ushort*)W3b, s2f, (ushort*)e2b);
  }
  // trailing U2(59), U3(59): segments [0,640)
  fusedD1<<<640, 256, 0, stream>>>(0, (const ushort*)A1, (const ushort*)W1b,
      (const ushort*)inb, (ushort*)e0, nullptr,
      (const ushort*)e1b, (const ushort*)W2T, s2f, (const ushort*)e2b,
      (ushort*)A2, (const ushort*)W3T, s3f, (ushort*)A3);

  k_copy_f32<<<cdiv(8192*10,256),256,0,stream>>>(out, s3f, 8192*10);
}